// Round 4
// baseline (257.862 us; speedup 1.0000x reference)
//
#include <hip/hip_runtime.h>
#include <hip/hip_bf16.h>
#include <stdint.h>
#include <math.h>

typedef unsigned short u16;
typedef __attribute__((ext_vector_type(8))) short short8;
typedef __attribute__((ext_vector_type(4))) float f32x4;
typedef __attribute__((ext_vector_type(16))) float f32x16;
typedef __attribute__((ext_vector_type(4))) unsigned int u32x4;
typedef __attribute__((ext_vector_type(2))) unsigned int u32x2;

#define NB 4
#define NS 2048
#define NH 12
#define HD 64
#define ND 768
#define ND3 2304

// scale * log2(e) folded into Q at QKV epilogue
#define QSCALE 0.18033688f

// ---------- helpers ----------
__device__ __forceinline__ u16 f2bf(float f) {
    unsigned int u = __float_as_uint(f);
    unsigned int r = u + 0x7fffu + ((u >> 16) & 1u);
    return (u16)(r >> 16);
}

// async global->LDS, 16B per lane; LDS dest = wave-uniform base + lane*16B
__device__ __forceinline__ void gload16(const u16* g, u16* s) {
    __builtin_amdgcn_global_load_lds(
        (const __attribute__((address_space(1))) unsigned int*)(const void*)g,
        (__attribute__((address_space(3))) unsigned int*)(void*)s, 16, 0, 0);
}

__device__ __forceinline__ unsigned int cvtpk(float lo, float hi) {
    unsigned int pk;
    asm("v_cvt_pk_bf16_f32 %0, %1, %2" : "=v"(pk) : "v"(lo), "v"(hi));
    return pk;
}

// ---------- fused fp32 -> bf16 casts (x, W_qkv, W_out) ----------
#define XN4   1572864
#define WQN4  442368
#define WON4  147456
__global__ __launch_bounds__(256) void castall(const float* __restrict__ x,
                                               const float* __restrict__ wq,
                                               const float* __restrict__ wo,
                                               u16* __restrict__ xb,
                                               u16* __restrict__ wqb,
                                               u16* __restrict__ wob) {
    int i = blockIdx.x * 256 + threadIdx.x;
    const float* s; u16* d; int j;
    if (i < XN4) { s = x; d = xb; j = i; }
    else if (i < XN4 + WQN4) { s = wq; d = wqb; j = i - XN4; }
    else if (i < XN4 + WQN4 + WON4) { s = wo; d = wob; j = i - XN4 - WQN4; }
    else return;
    float4 v = ((const float4*)s)[j];
    ushort4 o;
    o.x = f2bf(v.x); o.y = f2bf(v.y); o.z = f2bf(v.z); o.w = f2bf(v.w);
    ((ushort4*)d)[j] = o;
}

// ---------- QKV GEMM: C[8192][2304] = x_bf16 @ Wqkv_bf16^T + b ----------
// 64x192 tiles, grid (128,12) = 1536 blocks = 5/CU (LDS-capped): doubled
// block-level parallelism vs 128-tile so staggered blocks hide each other's
// per-K-step vmcnt(0) drain. 2-phase async pipeline (gload16 + LDS dbuf,
// one barrier per K-step). Epilogue scatters Q (scaled) -> Qg, K -> Kg,
// V -> Vtg^T.
__global__ __launch_bounds__(256, 5) void gemm_qkv(const u16* __restrict__ A,
                                                   const u16* __restrict__ Bw,
                                                   const float* __restrict__ bias,
                                                   u16* __restrict__ Qg,
                                                   u16* __restrict__ Kg,
                                                   u16* __restrict__ Vtg) {
    __shared__ u16 lds[2][8192]; // per buf: A chunks 0..3 (64x32), B chunks 4..15 (192x32)
    const int tid = threadIdx.x;
    const int w = tid >> 6, l = tid & 63;
    const int lam = l & 15, quad = l >> 4;
    const int wm = w >> 1, wn = w & 1;
    const int bm = blockIdx.x * 64;
    const int hh = blockIdx.y;          // head (192 cols per head)
    const int bn = hh * 192;
    const int K = ND;

    f32x4 acc[2][6];
#pragma unroll
    for (int i = 0; i < 2; i++)
#pragma unroll
        for (int j = 0; j < 6; j++) { f32x4 z = {0.f, 0.f, 0.f, 0.f}; acc[i][j] = z; }

    const u16* gp[4];
    int so[4]; // wave-uniform chunk base (u16 units) within a buffer
#pragma unroll
    for (int i = 0; i < 4; i++) {
        int c = w * 4 + i;
        if (c < 4) { gp[i] = A + (size_t)(bm + c * 16 + lam) * K + quad * 8; so[i] = c * 512; }
        else { int nf = c - 4; gp[i] = Bw + (size_t)(bn + nf * 16 + lam) * K + quad * 8; so[i] = 2048 + nf * 512; }
    }

    // prologue: stage tile 0, drain, barrier
#pragma unroll
    for (int i = 0; i < 4; i++) gload16(gp[i], &lds[0][so[i]]);
    asm volatile("s_waitcnt vmcnt(0)" ::: "memory");
    __syncthreads();

    int cur = 0;
    for (int k0 = 0; k0 < K; k0 += 32) {
        // issue next tile's stage first; lands during this tile's MFMAs
        if (k0 + 32 < K) {
#pragma unroll
            for (int i = 0; i < 4; i++) gload16(gp[i] + k0 + 32, &lds[cur ^ 1][so[i]]);
        }
        short8 a[2];
#pragma unroll
        for (int i = 0; i < 2; i++) a[i] = *(const short8*)(&lds[cur][(wm * 2 + i) * 512 + l * 8]);
#pragma unroll
        for (int half = 0; half < 2; half++) {
            short8 b[3];
#pragma unroll
            for (int j = 0; j < 3; j++) b[j] = *(const short8*)(&lds[cur][2048 + (wn * 6 + half * 3 + j) * 512 + l * 8]);
#pragma unroll
            for (int mf = 0; mf < 2; mf++)
#pragma unroll
                for (int j = 0; j < 3; j++)
                    acc[mf][half * 3 + j] = __builtin_amdgcn_mfma_f32_16x16x32_bf16(a[mf], b[j], acc[mf][half * 3 + j], 0, 0, 0);
        }
        // one barrier per K-step: waits own stage (vmcnt) + all waves' reads done
        asm volatile("s_waitcnt vmcnt(0)" ::: "memory");
        __syncthreads();
        cur ^= 1;
    }

    // epilogue: C row m = bm + wm*32 + mf*16 + quad*4 + r ; local col = wn*96 + nf*16 + lam
#pragma unroll
    for (int nf = 0; nf < 6; nf++) {
        int nloc = wn * 96 + nf * 16;       // wave-uniform, multiple of 16
        int rgn = nloc / 64;                // 0:Q 1:K 2:V (uniform; lam<16 never crosses)
        int d = (nloc % 64) + lam;
        float bv = bias[bn + nloc + lam];
        if (rgn == 2) {
#pragma unroll
            for (int mf = 0; mf < 2; mf++) {
                int m0 = bm + wm * 32 + mf * 16 + quad * 4;
                int bq = m0 >> 11, s0 = m0 & 2047;
                ushort4 o;
                o.x = f2bf(acc[mf][nf][0] + bv);
                o.y = f2bf(acc[mf][nf][1] + bv);
                o.z = f2bf(acc[mf][nf][2] + bv);
                o.w = f2bf(acc[mf][nf][3] + bv);
                *(ushort4*)(Vtg + ((size_t)((bq * NH + hh) * HD + d)) * NS + s0) = o;
            }
        } else {
            u16* dst = (rgn == 0) ? Qg : Kg;
            const float sc = (rgn == 0) ? QSCALE : 1.0f;
#pragma unroll
            for (int mf = 0; mf < 2; mf++)
#pragma unroll
                for (int r = 0; r < 4; r++) {
                    int m = bm + wm * 32 + mf * 16 + quad * 4 + r;
                    int bq = m >> 11, s = m & 2047;
                    dst[((size_t)((bq * NH + hh) * NS + s)) * HD + d] = f2bf((acc[mf][nf][r] + bv) * sc);
                }
        }
    }
}

// ---------- flash attention, P-in-register, full-rate PV via permlane32_swap ----------
// grid: 768 1-D; qt = bid/48, bh = bid%48 (XCD-local K/V). Block 256 = 4 waves.
// St = K.Q^T via 32x32x16 (C: col=q=lane&31, row=kpos=(r&3)+8(r>>2)+4h).
// P packed to bf16 pairs via v_cvt_pk_bf16_f32; permlane32_swap converts
// C-layout pairs into 32x32x16 A-frags. O += P.V; row-sum l = P.ones on the
// matrix pipe (C-layout -> per-lane rcp). NO setprio (splits scheduling
// regions; m190 null-to-negative in barrier-lockstep blocks).
__global__ __launch_bounds__(256, 3) void attn(const u16* __restrict__ Qg,
                                               const u16* __restrict__ Kg,
                                               const u16* __restrict__ Vtg,
                                               u16* __restrict__ ctx) {
    __shared__ u16 kt_lds[8192];  // 16 chunks (kg,s): lane L holds K[kg*32+(L&31)][s*16+(L>>5)*8+0..7]
    __shared__ u16 vt_lds[8192];  // 16 chunks c=(hg,tb): lane L = Vt[(c>>3)*32+(L&31)][(c&7)*16+(L>>5)*8+0..7]
    const int tid = threadIdx.x;
    const int w = tid >> 6, L = tid & 63;
    const int r5 = L & 31, h = L >> 5;
    const int bid = blockIdx.x;
    const int qt = bid / 48, bh = bid % 48;
    const int b = bh / NH, hd = bh % NH;
    const u16* Qh = Qg + (size_t)bh * NS * HD;
    const u16* Kh = Kg + (size_t)bh * NS * HD;
    const u16* Vh = Vtg + (size_t)bh * HD * NS;

    const int qbase = qt * 128 + w * 32;

    // Q B-frags (32x32x16): lane holds Q[q=r5][kd=s*16+h*8+0..7]
    short8 qf[4];
#pragma unroll
    for (int s = 0; s < 4; s++)
        qf[s] = *(const short8*)(Qh + (size_t)(qbase + r5) * HD + s * 16 + h * 8);

    f32x16 ot[2];
#pragma unroll
    for (int hg = 0; hg < 2; hg++)
#pragma unroll
        for (int r = 0; r < 16; r++) ot[hg][r] = 0.f;

    // row-sum accumulator (C-layout identical to ot rows); ones B-frag for P.1
    f32x16 lsum;
#pragma unroll
    for (int r = 0; r < 16; r++) lsum[r] = 0.f;
    short8 onesf;
#pragma unroll
    for (int i = 0; i < 8; i++) onesf[i] = (short)0x3F80;  // bf16 1.0

    // persistent zero C-operand for the QK mfma (laundered: stays in regs,
    // no 16 fresh v_movs per kg)
    f32x16 zero16;
#pragma unroll
    for (int r = 0; r < 16; r++) zero16[r] = 0.f;
    asm volatile("" : "+v"(zero16));

    // staging: waves 0-1 own the 16 K chunks, waves 2-3 the 16 Vt chunks.
    const u16* gp[8];
    u16* sp[8];
    int step;
    if (w < 2) {
#pragma unroll
        for (int i = 0; i < 8; i++) {
            int c = w * 8 + i, kg = c >> 2, s = c & 3;
            gp[i] = Kh + (size_t)(kg * 32 + r5) * HD + s * 16 + h * 8;
            sp[i] = kt_lds + c * 512;
        }
        step = 128 * HD;
    } else {
#pragma unroll
        for (int i = 0; i < 8; i++) {
            int c = (w - 2) * 8 + i;
            gp[i] = Vh + (size_t)((c >> 3) * 32 + r5) * NS + (c & 7) * 16 + h * 8;
            sp[i] = vt_lds + c * 512;
        }
        step = 128;
    }

    // preload tile kt=0
    u32x4 rg[8];
#pragma unroll
    for (int i = 0; i < 8; i++) { rg[i] = *(const u32x4*)gp[i]; gp[i] += step; }

    for (int kt = 0; kt < 16; kt++) {
        __syncthreads();   // prior tile's compute done -> LDS reusable
#pragma unroll
        for (int i = 0; i < 8; i++) *(u32x4*)(sp[i] + (size_t)L * 8) = rg[i];
        __syncthreads();

        // issue next tile's loads now; they complete during this tile's compute
        if (kt < 15) {
#pragma unroll
            for (int i = 0; i < 8; i++) { rg[i] = *(const u32x4*)gp[i]; gp[i] += step; }
        }

#pragma unroll
        for (int kg = 0; kg < 4; kg++) {
            // QK^T: 4 chained MFMAs, first uses persistent zero C (no re-init)
            short8 kf0 = *(const short8*)(kt_lds + (kg * 4 + 0) * 512 + L * 8);
            f32x16 st = __builtin_amdgcn_mfma_f32_32x32x16_bf16(kf0, qf[0], zero16, 0, 0, 0);
#pragma unroll
            for (int s = 1; s < 4; s++) {
                short8 kf = *(const short8*)(kt_lds + (kg * 4 + s) * 512 + L * 8);
                st = __builtin_amdgcn_mfma_f32_32x32x16_bf16(kf, qf[s], st, 0, 0, 0);
            }

            // exp2 -> pack pairs to bf16 via v_cvt_pk_bf16_f32 (RNE)
            float e[16];
#pragma unroll
            for (int i = 0; i < 16; i++) e[i] = __builtin_amdgcn_exp2f(st[i]);
            unsigned int q8[8];
#pragma unroll
            for (int i = 0; i < 8; i++) q8[i] = cvtpk(e[2 * i], e[2 * i + 1]);

            // cross-lane half-swaps -> A-frags for the two 16-t blocks of this kg
            u32x2 s02 = __builtin_amdgcn_permlane32_swap(q8[0], q8[2], false, false);
            u32x2 s13 = __builtin_amdgcn_permlane32_swap(q8[1], q8[3], false, false);
            u32x2 s46 = __builtin_amdgcn_permlane32_swap(q8[4], q8[6], false, false);
            u32x2 s57 = __builtin_amdgcn_permlane32_swap(q8[5], q8[7], false, false);
            union { u32x4 u; short8 s; } af0, af1;
            af0.u = (u32x4){s02.x, s13.x, s02.y, s13.y};
            af1.u = (u32x4){s46.x, s57.x, s46.y, s57.y};

            // row-sums on the matrix pipe: l += P.1
            lsum = __builtin_amdgcn_mfma_f32_32x32x16_bf16(af0.s, onesf, lsum, 0, 0, 0);
            lsum = __builtin_amdgcn_mfma_f32_32x32x16_bf16(af1.s, onesf, lsum, 0, 0, 0);
#pragma unroll
            for (int hg = 0; hg < 2; hg++) {
                short8 vf0 = *(const short8*)(vt_lds + (hg * 8 + kg * 2 + 0) * 512 + L * 8);
                short8 vf1 = *(const short8*)(vt_lds + (hg * 8 + kg * 2 + 1) * 512 + L * 8);
                ot[hg] = __builtin_amdgcn_mfma_f32_32x32x16_bf16(af0.s, vf0, ot[hg], 0, 0, 0);
                ot[hg] = __builtin_amdgcn_mfma_f32_32x32x16_bf16(af1.s, vf1, ot[hg], 0, 0, 0);
            }
        }
    }

    // epilogue: O C-layout: col hd' = r5, row q' = (r&3)+8*(r>>2)+4*h
    // lsum has the same row layout (cols replicated) -> pure per-lane scale.
    float inv[16];
#pragma unroll
    for (int r = 0; r < 16; r++) inv[r] = __builtin_amdgcn_rcpf(lsum[r]);
#pragma unroll
    for (int hg = 0; hg < 2; hg++) {
#pragma unroll
        for (int r = 0; r < 16; r++) {
            int q = qbase + (r & 3) + 8 * (r >> 2) + 4 * h;
            ctx[(size_t)(b * NS + q) * ND + hd * HD + hg * 32 + r5] = f2bf(ot[hg][r] * inv[r]);
        }
    }
}

// ---------- out projection: out[8192][768] = ctx_bf16 @ Wout_bf16^T + b ----------
// 64x96 tiles, grid (128,8) = 1024 blocks = 4/CU (was 2/CU at 128-tile):
// doubled block parallelism to hide the per-K-step stage latency. 2-phase
// async pipeline (gload16 + LDS dbuf, one barrier/K-step). 10 chunks staged
// by 4 waves x 3 slots; surplus slots duplicate chunks 0,1 (same data, same
// address: benign).
__global__ __launch_bounds__(256, 4) void gemm_out(const u16* __restrict__ A,
                                                   const u16* __restrict__ Bw,
                                                   const float* __restrict__ bias,
                                                   float* __restrict__ out) {
    __shared__ u16 lds[2][5120]; // per buf: A chunks 0..3, B chunks 4..9
    const int tid = threadIdx.x;
    const int w = tid >> 6, l = tid & 63;
    const int lam = l & 15, quad = l >> 4;
    const int wm = w >> 1, wn = w & 1;
    const int bm = blockIdx.x * 64, bn = blockIdx.y * 96;
    const int K = ND;

    f32x4 acc[2][3];
#pragma unroll
    for (int i = 0; i < 2; i++)
#pragma unroll
        for (int j = 0; j < 3; j++) { f32x4 z = {0.f, 0.f, 0.f, 0.f}; acc[i][j] = z; }

    const u16* gp[3];
    int so[3];
#pragma unroll
    for (int i = 0; i < 3; i++) {
        int c = w * 3 + i;
        if (c >= 10) c -= 10;   // duplicate-stage chunks 0,1 (benign)
        if (c < 4) { gp[i] = A + (size_t)(bm + c * 16 + lam) * K + quad * 8; so[i] = c * 512; }
        else { int nf = c - 4; gp[i] = Bw + (size_t)(bn + nf * 16 + lam) * K + quad * 8; so[i] = 2048 + nf * 512; }
    }

#pragma unroll
    for (int i = 0; i < 3; i++) gload16(gp[i], &lds[0][so[i]]);
    asm volatile("s_waitcnt vmcnt(0)" ::: "memory");
    __syncthreads();

    int cur = 0;
    for (int k0 = 0; k0 < K; k0 += 32) {
        if (k0 + 32 < K) {
#pragma unroll
            for (int i = 0; i < 3; i++) gload16(gp[i] + k0 + 32, &lds[cur ^ 1][so[i]]);
        }
        short8 a[2], b[3];
#pragma unroll
        for (int i = 0; i < 2; i++) a[i] = *(const short8*)(&lds[cur][(wm * 2 + i) * 512 + l * 8]);
#pragma unroll
        for (int j = 0; j < 3; j++) b[j] = *(const short8*)(&lds[cur][2048 + (wn * 3 + j) * 512 + l * 8]);
#pragma unroll
        for (int mf = 0; mf < 2; mf++)
#pragma unroll
            for (int j = 0; j < 3; j++)
                acc[mf][j] = __builtin_amdgcn_mfma_f32_16x16x32_bf16(a[mf], b[j], acc[mf][j], 0, 0, 0);
        asm volatile("s_waitcnt vmcnt(0)" ::: "memory");
        __syncthreads();
        cur ^= 1;
    }

#pragma unroll
    for (int nf = 0; nf < 3; nf++) {
        int n = bn + wn * 48 + nf * 16 + lam;
        float bv = bias[n];
#pragma unroll
        for (int mf = 0; mf < 2; mf++)
#pragma unroll
            for (int r = 0; r < 4; r++) {
                int m = bm + wm * 32 + mf * 16 + quad * 4 + r;
                out[(size_t)m * ND + n] = acc[mf][nf][r] + bv;
            }
    }
}

extern "C" void kernel_launch(void* const* d_in, const int* in_sizes, int n_in,
                              void* d_out, int out_size, void* d_ws, size_t ws_size,
                              hipStream_t stream) {
    const float* x    = (const float*)d_in[0];
    const float* Wqkv = (const float*)d_in[1];
    const float* bqkv = (const float*)d_in[2];
    const float* Wout = (const float*)d_in[3];
    const float* bout = (const float*)d_in[4];
    float* out = (float*)d_out;

    // workspace carve (bf16 elements)
    u16* p = (u16*)d_ws;
    u16* xb    = p; p += 6291456;  // x bf16 [8192][768]
    u16* wqkvb = p; p += 1769472;  // Wqkv bf16 [2304][768]
    u16* wob   = p; p += 589824;   // Wout bf16 [768][768]
    u16* Qg    = p; p += 6291456;  // [B,H,S,64] (pre-scaled by QSCALE)
    u16* Kg    = p; p += 6291456;  // [B,H,S,64]
    u16* Vtg   = p; p += 6291456;  // [B,H,64,S]
    u16* ctx   = p; p += 6291456;  // [8192][768]

    castall<<<8448, 256, 0, stream>>>(x, Wqkv, Wout, xb, wqkvb, wob);
    gemm_qkv<<<dim3(128, 12), 256, 0, stream>>>(xb, wqkvb, bqkv, Qg, Kg, Vtg);
    attn<<<768, 256, 0, stream>>>(Qg, Kg, Vtg, ctx);
    gemm_out<<<dim3(128, 8), 256, 0, stream>>>(ctx, wob, bout, out);
}

// Round 5
// 222.472 us; speedup vs baseline: 1.1591x; 1.1591x over previous
//
#include <hip/hip_runtime.h>
#include <hip/hip_bf16.h>
#include <stdint.h>
#include <math.h>

typedef unsigned short u16;
typedef __attribute__((ext_vector_type(8))) short short8;
typedef __attribute__((ext_vector_type(4))) float f32x4;
typedef __attribute__((ext_vector_type(16))) float f32x16;
typedef __attribute__((ext_vector_type(4))) unsigned int u32x4;
typedef __attribute__((ext_vector_type(2))) unsigned int u32x2;

#define NB 4
#define NS 2048
#define NH 12
#define HD 64
#define ND 768
#define ND3 2304

// scale * log2(e) folded into Q at QKV epilogue
#define QSCALE 0.18033688f

// ---------- helpers ----------
__device__ __forceinline__ u16 f2bf(float f) {
    unsigned int u = __float_as_uint(f);
    unsigned int r = u + 0x7fffu + ((u >> 16) & 1u);
    return (u16)(r >> 16);
}

// async global->LDS, 16B per lane; LDS dest = wave-uniform base + lane*16B
__device__ __forceinline__ void gload16(const u16* g, u16* s) {
    __builtin_amdgcn_global_load_lds(
        (const __attribute__((address_space(1))) unsigned int*)(const void*)g,
        (__attribute__((address_space(3))) unsigned int*)(void*)s, 16, 0, 0);
}

__device__ __forceinline__ unsigned int cvtpk(float lo, float hi) {
    unsigned int pk;
    asm("v_cvt_pk_bf16_f32 %0, %1, %2" : "=v"(pk) : "v"(lo), "v"(hi));
    return pk;
}

// ---------- fused fp32 -> bf16 casts (x, W_qkv, W_out) ----------
#define XN4   1572864
#define WQN4  442368
#define WON4  147456
__global__ __launch_bounds__(256) void castall(const float* __restrict__ x,
                                               const float* __restrict__ wq,
                                               const float* __restrict__ wo,
                                               u16* __restrict__ xb,
                                               u16* __restrict__ wqb,
                                               u16* __restrict__ wob) {
    int i = blockIdx.x * 256 + threadIdx.x;
    const float* s; u16* d; int j;
    if (i < XN4) { s = x; d = xb; j = i; }
    else if (i < XN4 + WQN4) { s = wq; d = wqb; j = i - XN4; }
    else if (i < XN4 + WQN4 + WON4) { s = wo; d = wob; j = i - XN4 - WQN4; }
    else return;
    float4 v = ((const float4*)s)[j];
    ushort4 o;
    o.x = f2bf(v.x); o.y = f2bf(v.y); o.z = f2bf(v.z); o.w = f2bf(v.w);
    ((ushort4*)d)[j] = o;
}

// ---------- QKV GEMM: C[8192][2304] = x_bf16 @ Wqkv_bf16^T + b ----------
// 128x192 tiles, grid (64,12). T3+T4 pipeline: 4 LDS buffers, 3-deep
// global_load_lds prefetch, COUNTED vmcnt (10/5/0 tail) + raw s_barrier —
// never drains vmcnt to 0 in the main loop (m218: counted-vs-drain0 is the
// whole gain; __syncthreads would force vmcnt(0)).
// Per iter t: wait vmcnt((D-1)*L) [stage t done] -> s_barrier [all waves'
// stage t done, all compute t-1 done] -> issue stage t+3 into buf[(t+3)%4]
// [= buf[(t-1)%4], free by barrier] -> compute buf[t%4].
// Epilogue scatters Q (scaled) -> Qg, K -> Kg, V -> Vtg^T.
__global__ __launch_bounds__(256, 2) void gemm_qkv(const u16* __restrict__ A,
                                                   const u16* __restrict__ Bw,
                                                   const float* __restrict__ bias,
                                                   u16* __restrict__ Qg,
                                                   u16* __restrict__ Kg,
                                                   u16* __restrict__ Vtg) {
    __shared__ u16 lds[4][10240]; // per buf: A chunks 0..7 (128x32), B chunks 8..19 (192x32)
    const int tid = threadIdx.x;
    const int w = tid >> 6, l = tid & 63;
    const int lam = l & 15, quad = l >> 4;
    const int wm = w >> 1, wn = w & 1;
    const int bm = blockIdx.x * 128;
    const int hh = blockIdx.y;          // head (192 cols per head)
    const int bn = hh * 192;
    const int NT = ND / 32;             // 24 K-steps

    f32x4 acc[4][6];
#pragma unroll
    for (int i = 0; i < 4; i++)
#pragma unroll
        for (int j = 0; j < 6; j++) { f32x4 z = {0.f, 0.f, 0.f, 0.f}; acc[i][j] = z; }

    const u16* gp[5];
    int so[5]; // wave-uniform chunk base (u16 units) within a buffer
#pragma unroll
    for (int i = 0; i < 5; i++) {
        int c = w * 5 + i;
        if (c < 8) { gp[i] = A + (size_t)(bm + c * 16 + lam) * ND + quad * 8; so[i] = c * 512; }
        else { int nf = c - 8; gp[i] = Bw + (size_t)(bn + nf * 16 + lam) * ND + quad * 8; so[i] = 4096 + nf * 512; }
    }

    // prologue: stage tiles 0,1,2 into bufs 0,1,2 (15 loads in flight/wave)
#pragma unroll
    for (int t = 0; t < 3; t++)
#pragma unroll
        for (int i = 0; i < 5; i++) gload16(gp[i] + t * 32, &lds[t][so[i]]);

    for (int t = 0; t < NT; ++t) {
        // counted wait: oldest stage (tile t) complete; 2 stages stay in flight
        if (t < NT - 2)      asm volatile("s_waitcnt vmcnt(10)" ::: "memory");
        else if (t == NT - 2) asm volatile("s_waitcnt vmcnt(5)" ::: "memory");
        else                 asm volatile("s_waitcnt vmcnt(0)" ::: "memory");
        __builtin_amdgcn_s_barrier();
        asm volatile("" ::: "memory");
        if (t + 3 < NT) {
#pragma unroll
            for (int i = 0; i < 5; i++) gload16(gp[i] + (t + 3) * 32, &lds[(t + 3) & 3][so[i]]);
        }
        const u16* buf = lds[t & 3];
        short8 a[4];
#pragma unroll
        for (int i = 0; i < 4; i++) a[i] = *(const short8*)(buf + (wm * 4 + i) * 512 + l * 8);
#pragma unroll
        for (int half = 0; half < 2; half++) {
            short8 b[3];
#pragma unroll
            for (int j = 0; j < 3; j++) b[j] = *(const short8*)(buf + 4096 + (wn * 6 + half * 3 + j) * 512 + l * 8);
#pragma unroll
            for (int mf = 0; mf < 4; mf++)
#pragma unroll
                for (int j = 0; j < 3; j++)
                    acc[mf][half * 3 + j] = __builtin_amdgcn_mfma_f32_16x16x32_bf16(a[mf], b[j], acc[mf][half * 3 + j], 0, 0, 0);
        }
    }

    // epilogue: C row m = bm + wm*64 + mf*16 + quad*4 + r ; local col = wn*96 + nf*16 + lam
#pragma unroll
    for (int nf = 0; nf < 6; nf++) {
        int nloc = wn * 96 + nf * 16;       // wave-uniform, multiple of 16
        int rgn = nloc / 64;                // 0:Q 1:K 2:V (uniform; lam<16 never crosses)
        int d = (nloc % 64) + lam;
        float bv = bias[bn + nloc + lam];
        if (rgn == 2) {
#pragma unroll
            for (int mf = 0; mf < 4; mf++) {
                int m0 = bm + wm * 64 + mf * 16 + quad * 4;
                int bq = m0 >> 11, s0 = m0 & 2047;
                ushort4 o;
                o.x = f2bf(acc[mf][nf][0] + bv);
                o.y = f2bf(acc[mf][nf][1] + bv);
                o.z = f2bf(acc[mf][nf][2] + bv);
                o.w = f2bf(acc[mf][nf][3] + bv);
                *(ushort4*)(Vtg + ((size_t)((bq * NH + hh) * HD + d)) * NS + s0) = o;
            }
        } else {
            u16* dst = (rgn == 0) ? Qg : Kg;
            const float sc = (rgn == 0) ? QSCALE : 1.0f;
#pragma unroll
            for (int mf = 0; mf < 4; mf++)
#pragma unroll
                for (int r = 0; r < 4; r++) {
                    int m = bm + wm * 64 + mf * 16 + quad * 4 + r;
                    int bq = m >> 11, s = m & 2047;
                    dst[((size_t)((bq * NH + hh) * NS + s)) * HD + d] = f2bf((acc[mf][nf][r] + bv) * sc);
                }
        }
    }
}

// ---------- flash attention, P-in-register, full-rate PV via permlane32_swap ----------
// grid: 768 1-D; qt = bid/48, bh = bid%48 (XCD-local K/V). Block 256 = 4 waves.
// St = K.Q^T via 32x32x16 (C: col=q=lane&31, row=kpos=(r&3)+8(r>>2)+4h).
// P packed to bf16 pairs via v_cvt_pk_bf16_f32; permlane32_swap converts
// C-layout pairs into 32x32x16 A-frags. O += P.V; row-sum l = P.ones on the
// matrix pipe (C-layout -> per-lane rcp). NO setprio (splits scheduling
// regions; m190 null-to-negative in barrier-lockstep blocks).
__global__ __launch_bounds__(256, 3) void attn(const u16* __restrict__ Qg,
                                               const u16* __restrict__ Kg,
                                               const u16* __restrict__ Vtg,
                                               u16* __restrict__ ctx) {
    __shared__ u16 kt_lds[8192];  // 16 chunks (kg,s): lane L holds K[kg*32+(L&31)][s*16+(L>>5)*8+0..7]
    __shared__ u16 vt_lds[8192];  // 16 chunks c=(hg,tb): lane L = Vt[(c>>3)*32+(L&31)][(c&7)*16+(L>>5)*8+0..7]
    const int tid = threadIdx.x;
    const int w = tid >> 6, L = tid & 63;
    const int r5 = L & 31, h = L >> 5;
    const int bid = blockIdx.x;
    const int qt = bid / 48, bh = bid % 48;
    const int b = bh / NH, hd = bh % NH;
    const u16* Qh = Qg + (size_t)bh * NS * HD;
    const u16* Kh = Kg + (size_t)bh * NS * HD;
    const u16* Vh = Vtg + (size_t)bh * HD * NS;

    const int qbase = qt * 128 + w * 32;

    // Q B-frags (32x32x16): lane holds Q[q=r5][kd=s*16+h*8+0..7]
    short8 qf[4];
#pragma unroll
    for (int s = 0; s < 4; s++)
        qf[s] = *(const short8*)(Qh + (size_t)(qbase + r5) * HD + s * 16 + h * 8);

    f32x16 ot[2];
#pragma unroll
    for (int hg = 0; hg < 2; hg++)
#pragma unroll
        for (int r = 0; r < 16; r++) ot[hg][r] = 0.f;

    // row-sum accumulator (C-layout identical to ot rows); ones B-frag for P.1
    f32x16 lsum;
#pragma unroll
    for (int r = 0; r < 16; r++) lsum[r] = 0.f;
    short8 onesf;
#pragma unroll
    for (int i = 0; i < 8; i++) onesf[i] = (short)0x3F80;  // bf16 1.0

    // persistent zero C-operand for the QK mfma (laundered: stays in regs,
    // no 16 fresh v_movs per kg)
    f32x16 zero16;
#pragma unroll
    for (int r = 0; r < 16; r++) zero16[r] = 0.f;
    asm volatile("" : "+v"(zero16));

    // staging: waves 0-1 own the 16 K chunks, waves 2-3 the 16 Vt chunks.
    const u16* gp[8];
    u16* sp[8];
    int step;
    if (w < 2) {
#pragma unroll
        for (int i = 0; i < 8; i++) {
            int c = w * 8 + i, kg = c >> 2, s = c & 3;
            gp[i] = Kh + (size_t)(kg * 32 + r5) * HD + s * 16 + h * 8;
            sp[i] = kt_lds + c * 512;
        }
        step = 128 * HD;
    } else {
#pragma unroll
        for (int i = 0; i < 8; i++) {
            int c = (w - 2) * 8 + i;
            gp[i] = Vh + (size_t)((c >> 3) * 32 + r5) * NS + (c & 7) * 16 + h * 8;
            sp[i] = vt_lds + c * 512;
        }
        step = 128;
    }

    // preload tile kt=0
    u32x4 rg[8];
#pragma unroll
    for (int i = 0; i < 8; i++) { rg[i] = *(const u32x4*)gp[i]; gp[i] += step; }

    for (int kt = 0; kt < 16; kt++) {
        __syncthreads();   // prior tile's compute done -> LDS reusable
#pragma unroll
        for (int i = 0; i < 8; i++) *(u32x4*)(sp[i] + (size_t)L * 8) = rg[i];
        __syncthreads();

        // issue next tile's loads now; they complete during this tile's compute
        if (kt < 15) {
#pragma unroll
            for (int i = 0; i < 8; i++) { rg[i] = *(const u32x4*)gp[i]; gp[i] += step; }
        }

#pragma unroll
        for (int kg = 0; kg < 4; kg++) {
            // QK^T: 4 chained MFMAs, first uses persistent zero C (no re-init)
            short8 kf0 = *(const short8*)(kt_lds + (kg * 4 + 0) * 512 + L * 8);
            f32x16 st = __builtin_amdgcn_mfma_f32_32x32x16_bf16(kf0, qf[0], zero16, 0, 0, 0);
#pragma unroll
            for (int s = 1; s < 4; s++) {
                short8 kf = *(const short8*)(kt_lds + (kg * 4 + s) * 512 + L * 8);
                st = __builtin_amdgcn_mfma_f32_32x32x16_bf16(kf, qf[s], st, 0, 0, 0);
            }

            // exp2 -> pack pairs to bf16 via v_cvt_pk_bf16_f32 (RNE)
            float e[16];
#pragma unroll
            for (int i = 0; i < 16; i++) e[i] = __builtin_amdgcn_exp2f(st[i]);
            unsigned int q8[8];
#pragma unroll
            for (int i = 0; i < 8; i++) q8[i] = cvtpk(e[2 * i], e[2 * i + 1]);

            // cross-lane half-swaps -> A-frags for the two 16-t blocks of this kg
            u32x2 s02 = __builtin_amdgcn_permlane32_swap(q8[0], q8[2], false, false);
            u32x2 s13 = __builtin_amdgcn_permlane32_swap(q8[1], q8[3], false, false);
            u32x2 s46 = __builtin_amdgcn_permlane32_swap(q8[4], q8[6], false, false);
            u32x2 s57 = __builtin_amdgcn_permlane32_swap(q8[5], q8[7], false, false);
            union { u32x4 u; short8 s; } af0, af1;
            af0.u = (u32x4){s02.x, s13.x, s02.y, s13.y};
            af1.u = (u32x4){s46.x, s57.x, s46.y, s57.y};

            // row-sums on the matrix pipe: l += P.1
            lsum = __builtin_amdgcn_mfma_f32_32x32x16_bf16(af0.s, onesf, lsum, 0, 0, 0);
            lsum = __builtin_amdgcn_mfma_f32_32x32x16_bf16(af1.s, onesf, lsum, 0, 0, 0);
#pragma unroll
            for (int hg = 0; hg < 2; hg++) {
                short8 vf0 = *(const short8*)(vt_lds + (hg * 8 + kg * 2 + 0) * 512 + L * 8);
                short8 vf1 = *(const short8*)(vt_lds + (hg * 8 + kg * 2 + 1) * 512 + L * 8);
                ot[hg] = __builtin_amdgcn_mfma_f32_32x32x16_bf16(af0.s, vf0, ot[hg], 0, 0, 0);
                ot[hg] = __builtin_amdgcn_mfma_f32_32x32x16_bf16(af1.s, vf1, ot[hg], 0, 0, 0);
            }
        }
    }

    // epilogue: O C-layout: col hd' = r5, row q' = (r&3)+8*(r>>2)+4*h
    // lsum has the same row layout (cols replicated) -> pure per-lane scale.
    float inv[16];
#pragma unroll
    for (int r = 0; r < 16; r++) inv[r] = __builtin_amdgcn_rcpf(lsum[r]);
#pragma unroll
    for (int hg = 0; hg < 2; hg++) {
#pragma unroll
        for (int r = 0; r < 16; r++) {
            int q = qbase + (r & 3) + 8 * (r >> 2) + 4 * h;
            ctx[(size_t)(b * NS + q) * ND + hd * HD + hg * 32 + r5] = f2bf(ot[hg][r] * inv[r]);
        }
    }
}

// ---------- out projection: out[8192][768] = ctx_bf16 @ Wout_bf16^T + b ----------
// 128x96 tiles, grid (64,8) = 512 blocks = 2/CU. Same T3+T4 pipeline as
// gemm_qkv: 4 LDS buffers, 3-deep prefetch, counted vmcnt (8/4/0 tail),
// raw s_barrier. 14 chunks staged by 4 waves x 4 slots; w3's surplus slots
// duplicate chunks 0,1 (same data, same address: benign).
__global__ __launch_bounds__(256, 2) void gemm_out(const u16* __restrict__ A,
                                                   const u16* __restrict__ Bw,
                                                   const float* __restrict__ bias,
                                                   float* __restrict__ out) {
    __shared__ u16 lds[4][7168]; // per buf: A chunks 0..7, B chunks 8..13
    const int tid = threadIdx.x;
    const int w = tid >> 6, l = tid & 63;
    const int lam = l & 15, quad = l >> 4;
    const int wm = w >> 1, wn = w & 1;
    const int bm = blockIdx.x * 128, bn = blockIdx.y * 96;
    const int NT = ND / 32;             // 24 K-steps

    f32x4 acc[4][3];
#pragma unroll
    for (int i = 0; i < 4; i++)
#pragma unroll
        for (int j = 0; j < 3; j++) { f32x4 z = {0.f, 0.f, 0.f, 0.f}; acc[i][j] = z; }

    const u16* gp[4];
    int so[4];
#pragma unroll
    for (int i = 0; i < 4; i++) {
        int c = w * 4 + i;
        if (c >= 14) c -= 14;   // duplicate-stage chunks 0,1 (benign)
        if (c < 8) { gp[i] = A + (size_t)(bm + c * 16 + lam) * ND + quad * 8; so[i] = c * 512; }
        else { int nf = c - 8; gp[i] = Bw + (size_t)(bn + nf * 16 + lam) * ND + quad * 8; so[i] = 4096 + nf * 512; }
    }

    // prologue: stage tiles 0,1,2 into bufs 0,1,2
#pragma unroll
    for (int t = 0; t < 3; t++)
#pragma unroll
        for (int i = 0; i < 4; i++) gload16(gp[i] + t * 32, &lds[t][so[i]]);

    for (int t = 0; t < NT; ++t) {
        if (t < NT - 2)      asm volatile("s_waitcnt vmcnt(8)" ::: "memory");
        else if (t == NT - 2) asm volatile("s_waitcnt vmcnt(4)" ::: "memory");
        else                 asm volatile("s_waitcnt vmcnt(0)" ::: "memory");
        __builtin_amdgcn_s_barrier();
        asm volatile("" ::: "memory");
        if (t + 3 < NT) {
#pragma unroll
            for (int i = 0; i < 4; i++) gload16(gp[i] + (t + 3) * 32, &lds[(t + 3) & 3][so[i]]);
        }
        const u16* buf = lds[t & 3];
        short8 a[4], b[3];
#pragma unroll
        for (int i = 0; i < 4; i++) a[i] = *(const short8*)(buf + (wm * 4 + i) * 512 + l * 8);
#pragma unroll
        for (int j = 0; j < 3; j++) b[j] = *(const short8*)(buf + 4096 + (wn * 3 + j) * 512 + l * 8);
#pragma unroll
        for (int mf = 0; mf < 4; mf++)
#pragma unroll
            for (int j = 0; j < 3; j++)
                acc[mf][j] = __builtin_amdgcn_mfma_f32_16x16x32_bf16(a[mf], b[j], acc[mf][j], 0, 0, 0);
    }

#pragma unroll
    for (int nf = 0; nf < 3; nf++) {
        int n = bn + wn * 48 + nf * 16 + lam;
        float bv = bias[n];
#pragma unroll
        for (int mf = 0; mf < 4; mf++)
#pragma unroll
            for (int r = 0; r < 4; r++) {
                int m = bm + wm * 64 + mf * 16 + quad * 4 + r;
                out[(size_t)m * ND + n] = acc[mf][nf][r] + bv;
            }
    }
}

extern "C" void kernel_launch(void* const* d_in, const int* in_sizes, int n_in,
                              void* d_out, int out_size, void* d_ws, size_t ws_size,
                              hipStream_t stream) {
    const float* x    = (const float*)d_in[0];
    const float* Wqkv = (const float*)d_in[1];
    const float* bqkv = (const float*)d_in[2];
    const float* Wout = (const float*)d_in[3];
    const float* bout = (const float*)d_in[4];
    float* out = (float*)d_out;

    // workspace carve (bf16 elements)
    u16* p = (u16*)d_ws;
    u16* xb    = p; p += 6291456;  // x bf16 [8192][768]
    u16* wqkvb = p; p += 1769472;  // Wqkv bf16 [2304][768]
    u16* wob   = p; p += 589824;   // Wout bf16 [768][768]
    u16* Qg    = p; p += 6291456;  // [B,H,S,64] (pre-scaled by QSCALE)
    u16* Kg    = p; p += 6291456;  // [B,H,S,64]
    u16* Vtg   = p; p += 6291456;  // [B,H,64,S]
    u16* ctx   = p; p += 6291456;  // [8192][768]

    castall<<<8448, 256, 0, stream>>>(x, Wqkv, Wout, xb, wqkvb, wob);
    gemm_qkv<<<dim3(64, 12), 256, 0, stream>>>(xb, wqkvb, bqkv, Qg, Kg, Vtg);
    attn<<<768, 256, 0, stream>>>(Qg, Kg, Vtg, ctx);
    gemm_out<<<dim3(64, 8), 256, 0, stream>>>(ctx, wob, bout, out);
}

// Round 7
// 217.017 us; speedup vs baseline: 1.1882x; 1.0251x over previous
//
#include <hip/hip_runtime.h>
#include <hip/hip_bf16.h>
#include <stdint.h>
#include <math.h>

typedef unsigned short u16;
typedef __attribute__((ext_vector_type(8))) short short8;
typedef __attribute__((ext_vector_type(4))) float f32x4;
typedef __attribute__((ext_vector_type(16))) float f32x16;
typedef __attribute__((ext_vector_type(4))) unsigned int u32x4;
typedef __attribute__((ext_vector_type(2))) unsigned int u32x2;

#define NB 4
#define NS 2048
#define NH 12
#define HD 64
#define ND 768
#define ND3 2304

// scale * log2(e) folded into Q at QKV epilogue
#define QSCALE 0.18033688f

// ---------- helpers ----------
__device__ __forceinline__ u16 f2bf(float f) {
    unsigned int u = __float_as_uint(f);
    unsigned int r = u + 0x7fffu + ((u >> 16) & 1u);
    return (u16)(r >> 16);
}

// async global->LDS, 16B per lane; LDS dest = wave-uniform base + lane*16B
__device__ __forceinline__ void gload16(const u16* g, u16* s) {
    __builtin_amdgcn_global_load_lds(
        (const __attribute__((address_space(1))) unsigned int*)(const void*)g,
        (__attribute__((address_space(3))) unsigned int*)(void*)s, 16, 0, 0);
}

__device__ __forceinline__ unsigned int cvtpk(float lo, float hi) {
    unsigned int pk;
    asm("v_cvt_pk_bf16_f32 %0, %1, %2" : "=v"(pk) : "v"(lo), "v"(hi));
    return pk;
}

// ---------- fused fp32 -> bf16 casts (x, W_qkv, W_out) ----------
#define XN4   1572864
#define WQN4  442368
#define WON4  147456
__global__ __launch_bounds__(256) void castall(const float* __restrict__ x,
                                               const float* __restrict__ wq,
                                               const float* __restrict__ wo,
                                               u16* __restrict__ xb,
                                               u16* __restrict__ wqb,
                                               u16* __restrict__ wob) {
    int i = blockIdx.x * 256 + threadIdx.x;
    const float* s; u16* d; int j;
    if (i < XN4) { s = x; d = xb; j = i; }
    else if (i < XN4 + WQN4) { s = wq; d = wqb; j = i - XN4; }
    else if (i < XN4 + WQN4 + WON4) { s = wo; d = wob; j = i - XN4 - WQN4; }
    else return;
    float4 v = ((const float4*)s)[j];
    ushort4 o;
    o.x = f2bf(v.x); o.y = f2bf(v.y); o.z = f2bf(v.z); o.w = f2bf(v.w);
    ((ushort4*)d)[j] = o;
}

// ---------- QKV GEMM: C[8192][2304] = x_bf16 @ Wqkv_bf16^T + b ----------
// 128x192 tiles, grid (64,12). T3+T4 pipeline: 4 LDS buffers, 3-deep
// global_load_lds prefetch, COUNTED vmcnt (10/5/0 tail) + raw s_barrier.
// (R5 structure, unchanged — serves as control this round.)
__global__ __launch_bounds__(256, 2) void gemm_qkv(const u16* __restrict__ A,
                                                   const u16* __restrict__ Bw,
                                                   const float* __restrict__ bias,
                                                   u16* __restrict__ Qg,
                                                   u16* __restrict__ Kg,
                                                   u16* __restrict__ Vtg) {
    __shared__ u16 lds[4][10240]; // per buf: A chunks 0..7 (128x32), B chunks 8..19 (192x32)
    const int tid = threadIdx.x;
    const int w = tid >> 6, l = tid & 63;
    const int lam = l & 15, quad = l >> 4;
    const int wm = w >> 1, wn = w & 1;
    const int bm = blockIdx.x * 128;
    const int hh = blockIdx.y;          // head (192 cols per head)
    const int bn = hh * 192;
    const int NT = ND / 32;             // 24 K-steps

    f32x4 acc[4][6];
#pragma unroll
    for (int i = 0; i < 4; i++)
#pragma unroll
        for (int j = 0; j < 6; j++) { f32x4 z = {0.f, 0.f, 0.f, 0.f}; acc[i][j] = z; }

    const u16* gp[5];
    int so[5]; // wave-uniform chunk base (u16 units) within a buffer
#pragma unroll
    for (int i = 0; i < 5; i++) {
        int c = w * 5 + i;
        if (c < 8) { gp[i] = A + (size_t)(bm + c * 16 + lam) * ND + quad * 8; so[i] = c * 512; }
        else { int nf = c - 8; gp[i] = Bw + (size_t)(bn + nf * 16 + lam) * ND + quad * 8; so[i] = 4096 + nf * 512; }
    }

    // prologue: stage tiles 0,1,2 into bufs 0,1,2 (15 loads in flight/wave)
#pragma unroll
    for (int t = 0; t < 3; t++)
#pragma unroll
        for (int i = 0; i < 5; i++) gload16(gp[i] + t * 32, &lds[t][so[i]]);

    for (int t = 0; t < NT; ++t) {
        // counted wait: oldest stage (tile t) complete; 2 stages stay in flight
        if (t < NT - 2)      asm volatile("s_waitcnt vmcnt(10)" ::: "memory");
        else if (t == NT - 2) asm volatile("s_waitcnt vmcnt(5)" ::: "memory");
        else                 asm volatile("s_waitcnt vmcnt(0)" ::: "memory");
        __builtin_amdgcn_s_barrier();
        asm volatile("" ::: "memory");
        if (t + 3 < NT) {
#pragma unroll
            for (int i = 0; i < 5; i++) gload16(gp[i] + (t + 3) * 32, &lds[(t + 3) & 3][so[i]]);
        }
        const u16* buf = lds[t & 3];
        short8 a[4];
#pragma unroll
        for (int i = 0; i < 4; i++) a[i] = *(const short8*)(buf + (wm * 4 + i) * 512 + l * 8);
#pragma unroll
        for (int half = 0; half < 2; half++) {
            short8 b[3];
#pragma unroll
            for (int j = 0; j < 3; j++) b[j] = *(const short8*)(buf + 4096 + (wn * 6 + half * 3 + j) * 512 + l * 8);
#pragma unroll
            for (int mf = 0; mf < 4; mf++)
#pragma unroll
                for (int j = 0; j < 3; j++)
                    acc[mf][half * 3 + j] = __builtin_amdgcn_mfma_f32_16x16x32_bf16(a[mf], b[j], acc[mf][half * 3 + j], 0, 0, 0);
        }
    }

    // epilogue: C row m = bm + wm*64 + mf*16 + quad*4 + r ; local col = wn*96 + nf*16 + lam
#pragma unroll
    for (int nf = 0; nf < 6; nf++) {
        int nloc = wn * 96 + nf * 16;       // wave-uniform, multiple of 16
        int rgn = nloc / 64;                // 0:Q 1:K 2:V (uniform; lam<16 never crosses)
        int d = (nloc % 64) + lam;
        float bv = bias[bn + nloc + lam];
        if (rgn == 2) {
#pragma unroll
            for (int mf = 0; mf < 4; mf++) {
                int m0 = bm + wm * 64 + mf * 16 + quad * 4;
                int bq = m0 >> 11, s0 = m0 & 2047;
                ushort4 o;
                o.x = f2bf(acc[mf][nf][0] + bv);
                o.y = f2bf(acc[mf][nf][1] + bv);
                o.z = f2bf(acc[mf][nf][2] + bv);
                o.w = f2bf(acc[mf][nf][3] + bv);
                *(ushort4*)(Vtg + ((size_t)((bq * NH + hh) * HD + d)) * NS + s0) = o;
            }
        } else {
            u16* dst = (rgn == 0) ? Qg : Kg;
            const float sc = (rgn == 0) ? QSCALE : 1.0f;
#pragma unroll
            for (int mf = 0; mf < 4; mf++)
#pragma unroll
                for (int r = 0; r < 4; r++) {
                    int m = bm + wm * 64 + mf * 16 + quad * 4 + r;
                    int bq = m >> 11, s = m & 2047;
                    dst[((size_t)((bq * NH + hh) * NS + s)) * HD + d] = f2bf((acc[mf][nf][r] + bv) * sc);
                }
        }
    }
}

// ---------- flash attention, P-in-register, full-rate PV via permlane32_swap ----------
// grid: 768 1-D; qt = bid/48, bh = bid%48 (XCD-local K/V). Block 256 = 4 waves.
// KVBLK=64 tiles, T3+T4 staging: 3 LDS buffers (16 KB each = 48 KB -> keeps
// 3 blocks/CU), depth-2 global_load_lds prefetch, counted vmcnt(4) + ONE raw
// s_barrier per tile. No ds_writes, no staging VGPRs. Each wave waits its own
// stage-t loads (vmcnt) BEFORE the barrier -> after barrier all K/V of tile t
// is LDS-resident (R5-gemm idiom, refcheck-proven).
// St = K.Q^T via 32x32x16; P packed to bf16 via v_cvt_pk_bf16_f32;
// permlane32_swap -> A-frags; O += P.V; row-sum l = P.ones on matrix pipe.
__global__ __launch_bounds__(256, 3) void attn(const u16* __restrict__ Qg,
                                               const u16* __restrict__ Kg,
                                               const u16* __restrict__ Vtg,
                                               u16* __restrict__ ctx) {
    // per buf: K chunks 0..7 (64 kpos x 64 d), V chunks 8..15 (Vt 64 hd x 64 t)
    __shared__ u16 kv_lds[3][8192];
    const int tid = threadIdx.x;
    const int w = tid >> 6, L = tid & 63;
    const int r5 = L & 31, h = L >> 5;
    const int bid = blockIdx.x;
    const int qt = bid / 48, bh = bid % 48;
    const int b = bh / NH, hd = bh % NH;
    const u16* Qh = Qg + (size_t)bh * NS * HD;
    const u16* Kh = Kg + (size_t)bh * NS * HD;
    const u16* Vh = Vtg + (size_t)bh * HD * NS;

    const int qbase = qt * 128 + w * 32;

    // Q B-frags (32x32x16): lane holds Q[q=r5][kd=s*16+h*8+0..7]
    short8 qf[4];
#pragma unroll
    for (int s = 0; s < 4; s++)
        qf[s] = *(const short8*)(Qh + (size_t)(qbase + r5) * HD + s * 16 + h * 8);

    f32x16 ot[2];
#pragma unroll
    for (int hg = 0; hg < 2; hg++)
#pragma unroll
        for (int r = 0; r < 16; r++) ot[hg][r] = 0.f;

    // row-sum accumulator (C-layout identical to ot rows); ones B-frag for P.1
    f32x16 lsum;
#pragma unroll
    for (int r = 0; r < 16; r++) lsum[r] = 0.f;
    short8 onesf;
#pragma unroll
    for (int i = 0; i < 8; i++) onesf[i] = (short)0x3F80;  // bf16 1.0

    // persistent zero C-operand for the QK mfma (laundered: stays in regs)
    f32x16 zero16;
#pragma unroll
    for (int r = 0; r < 16; r++) zero16[r] = 0.f;
    asm volatile("" : "+v"(zero16));

    // staging: 16 chunks / 4 waves = 4 chunks per wave.
    // waves 0-1: K chunks 0..7; waves 2-3: V chunks 8..15.
    const u16* gp[4];
    int so[4];
    int step;
    if (w < 2) {
#pragma unroll
        for (int i = 0; i < 4; i++) {
            int c = w * 4 + i;                 // 0..7
            int kg = c >> 2, s = c & 3;
            gp[i] = Kh + (size_t)(kg * 32 + r5) * HD + s * 16 + h * 8;
            so[i] = c * 512;
        }
        step = 64 * HD;
    } else {
#pragma unroll
        for (int i = 0; i < 4; i++) {
            int v = (w - 2) * 4 + i;           // 0..7
            int hg = v >> 2, tb = v & 3;
            gp[i] = Vh + (size_t)(hg * 32 + r5) * NS + tb * 16 + h * 8;
            so[i] = (8 + v) * 512;
        }
        step = 64;
    }

    const int NT = NS / 64;  // 32 tiles
    // prologue: stage tiles 0,1 into bufs 0,1 (8 loads in flight per wave)
#pragma unroll
    for (int t = 0; t < 2; t++)
#pragma unroll
        for (int i = 0; i < 4; i++) gload16(gp[i] + (size_t)t * step, &kv_lds[t][so[i]]);

    int cur = 0, nx2 = 2;   // kt%3 and (kt+2)%3, manually rotated
    for (int kt = 0; kt < NT; kt++) {
        // own stage-t loads done (stage t+1 stays in flight), then barrier:
        // all waves' tile-t chunks resident + all compute of t-1 finished.
        if (kt < NT - 1) asm volatile("s_waitcnt vmcnt(4)" ::: "memory");
        else             asm volatile("s_waitcnt vmcnt(0)" ::: "memory");
        __builtin_amdgcn_s_barrier();
        asm volatile("" ::: "memory");
        if (kt + 2 < NT) {
#pragma unroll
            for (int i = 0; i < 4; i++) gload16(gp[i] + (size_t)(kt + 2) * step, &kv_lds[nx2][so[i]]);
        }
        const u16* buf = kv_lds[cur];

#pragma unroll
        for (int kg = 0; kg < 2; kg++) {
            // QK^T: 4 chained MFMAs, first uses persistent zero C (no re-init)
            short8 kf0 = *(const short8*)(buf + (kg * 4 + 0) * 512 + L * 8);
            f32x16 st = __builtin_amdgcn_mfma_f32_32x32x16_bf16(kf0, qf[0], zero16, 0, 0, 0);
#pragma unroll
            for (int s = 1; s < 4; s++) {
                short8 kf = *(const short8*)(buf + (kg * 4 + s) * 512 + L * 8);
                st = __builtin_amdgcn_mfma_f32_32x32x16_bf16(kf, qf[s], st, 0, 0, 0);
            }

            // exp2 -> pack pairs to bf16 via v_cvt_pk_bf16_f32 (RNE)
            float e[16];
#pragma unroll
            for (int i = 0; i < 16; i++) e[i] = __builtin_amdgcn_exp2f(st[i]);
            unsigned int q8[8];
#pragma unroll
            for (int i = 0; i < 8; i++) q8[i] = cvtpk(e[2 * i], e[2 * i + 1]);

            // cross-lane half-swaps -> A-frags for the two 16-t blocks of this kg
            u32x2 s02 = __builtin_amdgcn_permlane32_swap(q8[0], q8[2], false, false);
            u32x2 s13 = __builtin_amdgcn_permlane32_swap(q8[1], q8[3], false, false);
            u32x2 s46 = __builtin_amdgcn_permlane32_swap(q8[4], q8[6], false, false);
            u32x2 s57 = __builtin_amdgcn_permlane32_swap(q8[5], q8[7], false, false);
            union { u32x4 u; short8 s; } af0, af1;
            af0.u = (u32x4){s02.x, s13.x, s02.y, s13.y};
            af1.u = (u32x4){s46.x, s57.x, s46.y, s57.y};

            // row-sums on the matrix pipe: l += P.1
            lsum = __builtin_amdgcn_mfma_f32_32x32x16_bf16(af0.s, onesf, lsum, 0, 0, 0);
            lsum = __builtin_amdgcn_mfma_f32_32x32x16_bf16(af1.s, onesf, lsum, 0, 0, 0);
#pragma unroll
            for (int hg = 0; hg < 2; hg++) {
                short8 vf0 = *(const short8*)(buf + (8 + hg * 4 + kg * 2 + 0) * 512 + L * 8);
                short8 vf1 = *(const short8*)(buf + (8 + hg * 4 + kg * 2 + 1) * 512 + L * 8);
                ot[hg] = __builtin_amdgcn_mfma_f32_32x32x16_bf16(af0.s, vf0, ot[hg], 0, 0, 0);
                ot[hg] = __builtin_amdgcn_mfma_f32_32x32x16_bf16(af1.s, vf1, ot[hg], 0, 0, 0);
            }
        }
        cur = (cur == 2) ? 0 : cur + 1;
        nx2 = (nx2 == 2) ? 0 : nx2 + 1;
    }

    // epilogue: O C-layout: col hd' = r5, row q' = (r&3)+8*(r>>2)+4*h
    // lsum has the same row layout (cols replicated) -> pure per-lane scale.
    float inv[16];
#pragma unroll
    for (int r = 0; r < 16; r++) inv[r] = __builtin_amdgcn_rcpf(lsum[r]);
#pragma unroll
    for (int hg = 0; hg < 2; hg++) {
#pragma unroll
        for (int r = 0; r < 16; r++) {
            int q = qbase + (r & 3) + 8 * (r >> 2) + 4 * h;
            ctx[(size_t)(b * NS + q) * ND + hd * HD + hg * 32 + r5] = f2bf(ot[hg][r] * inv[r]);
        }
    }
}

// ---------- out projection: out[8192][768] = ctx_bf16 @ Wout_bf16^T + b ----------
// 128x96 tiles, grid (64,8) = 512 blocks = 2/CU. T3+T4 pipeline (R5
// structure, unchanged — control this round).
__global__ __launch_bounds__(256, 2) void gemm_out(const u16* __restrict__ A,
                                                   const u16* __restrict__ Bw,
                                                   const float* __restrict__ bias,
                                                   float* __restrict__ out) {
    __shared__ u16 lds[4][7168]; // per buf: A chunks 0..7, B chunks 8..13
    const int tid = threadIdx.x;
    const int w = tid >> 6, l = tid & 63;
    const int lam = l & 15, quad = l >> 4;
    const int wm = w >> 1, wn = w & 1;
    const int bm = blockIdx.x * 128, bn = blockIdx.y * 96;
    const int NT = ND / 32;             // 24 K-steps

    f32x4 acc[4][3];
#pragma unroll
    for (int i = 0; i < 4; i++)
#pragma unroll
        for (int j = 0; j < 3; j++) { f32x4 z = {0.f, 0.f, 0.f, 0.f}; acc[i][j] = z; }

    const u16* gp[4];
    int so[4];
#pragma unroll
    for (int i = 0; i < 4; i++) {
        int c = w * 4 + i;
        if (c >= 14) c -= 14;   // duplicate-stage chunks 0,1 (benign)
        if (c < 8) { gp[i] = A + (size_t)(bm + c * 16 + lam) * ND + quad * 8; so[i] = c * 512; }
        else { int nf = c - 8; gp[i] = Bw + (size_t)(bn + nf * 16 + lam) * ND + quad * 8; so[i] = 4096 + nf * 512; }
    }

    // prologue: stage tiles 0,1,2 into bufs 0,1,2
#pragma unroll
    for (int t = 0; t < 3; t++)
#pragma unroll
        for (int i = 0; i < 4; i++) gload16(gp[i] + t * 32, &lds[t][so[i]]);

    for (int t = 0; t < NT; ++t) {
        if (t < NT - 2)      asm volatile("s_waitcnt vmcnt(8)" ::: "memory");
        else if (t == NT - 2) asm volatile("s_waitcnt vmcnt(4)" ::: "memory");
        else                 asm volatile("s_waitcnt vmcnt(0)" ::: "memory");
        __builtin_amdgcn_s_barrier();
        asm volatile("" ::: "memory");
        if (t + 3 < NT) {
#pragma unroll
            for (int i = 0; i < 4; i++) gload16(gp[i] + (t + 3) * 32, &lds[(t + 3) & 3][so[i]]);
        }
        const u16* buf = lds[t & 3];
        short8 a[4], b[3];
#pragma unroll
        for (int i = 0; i < 4; i++) a[i] = *(const short8*)(buf + (wm * 4 + i) * 512 + l * 8);
#pragma unroll
        for (int j = 0; j < 3; j++) b[j] = *(const short8*)(buf + 4096 + (wn * 3 + j) * 512 + l * 8);
#pragma unroll
        for (int mf = 0; mf < 4; mf++)
#pragma unroll
            for (int j = 0; j < 3; j++)
                acc[mf][j] = __builtin_amdgcn_mfma_f32_16x16x32_bf16(a[mf], b[j], acc[mf][j], 0, 0, 0);
    }

#pragma unroll
    for (int nf = 0; nf < 3; nf++) {
        int n = bn + wn * 48 + nf * 16 + lam;
        float bv = bias[n];
#pragma unroll
        for (int mf = 0; mf < 4; mf++)
#pragma unroll
            for (int r = 0; r < 4; r++) {
                int m = bm + wm * 64 + mf * 16 + quad * 4 + r;
                out[(size_t)m * ND + n] = acc[mf][nf][r] + bv;
            }
    }
}

extern "C" void kernel_launch(void* const* d_in, const int* in_sizes, int n_in,
                              void* d_out, int out_size, void* d_ws, size_t ws_size,
                              hipStream_t stream) {
    const float* x    = (const float*)d_in[0];
    const float* Wqkv = (const float*)d_in[1];
    const float* bqkv = (const float*)d_in[2];
    const float* Wout = (const float*)d_in[3];
    const float* bout = (const float*)d_in[4];
    float* out = (float*)d_out;

    // workspace carve (bf16 elements)
    u16* p = (u16*)d_ws;
    u16* xb    = p; p += 6291456;  // x bf16 [8192][768]
    u16* wqkvb = p; p += 1769472;  // Wqkv bf16 [2304][768]
    u16* wob   = p; p += 589824;   // Wout bf16 [768][768]
    u16* Qg    = p; p += 6291456;  // [B,H,S,64] (pre-scaled by QSCALE)
    u16* Kg    = p; p += 6291456;  // [B,H,S,64]
    u16* Vtg   = p; p += 6291456;  // [B,H,64,S]
    u16* ctx   = p; p += 6291456;  // [8192][768]

    castall<<<8448, 256, 0, stream>>>(x, Wqkv, Wout, xb, wqkvb, wob);
    gemm_qkv<<<dim3(64, 12), 256, 0, stream>>>(xb, wqkvb, bqkv, Qg, Kg, Vtg);
    attn<<<768, 256, 0, stream>>>(Qg, Kg, Vtg, ctx);
    gemm_out<<<dim3(64, 8), 256, 0, stream>>>(ctx, wob, bout, out);
}